// Round 1
// baseline (766.793 us; speedup 1.0000x reference)
//
#include <hip/hip_runtime.h>
#include <cstddef>
#include <cstdint>

#define B_DIM 8
#define L_DIM 2048
#define H_DIM 512
#define N_DIM 64
#define HN (H_DIM * N_DIM)          // 32768
#define BLH (B_DIM * L_DIM * H_DIM) // 8388608

__device__ __forceinline__ float sigmoidf_(float v) {
    return 1.0f / (1.0f + __expf(-v));
}

// jax.nn.gelu default: approximate=True (tanh form)
__device__ __forceinline__ float gelu_tanh_(float x) {
    float x3 = x * x * x;
    float z = 0.7978845608028654f * fmaf(0.044715f, x3, x);
    float e = __expf(-2.0f * fabsf(z));
    float th = (1.0f - e) / (1.0f + e);
    th = copysignf(th, z);
    return 0.5f * x * (1.0f + th);
}

// ---------------------------------------------------------------------------
// 1) Per-(h,n) SSM params: w = exp(dt*A), Ct2 = 2*C*(exp(dt*A)-1)/A
// ---------------------------------------------------------------------------
__global__ __launch_bounds__(256) void precompute_kernel(
    const float* __restrict__ log_dt, const float* __restrict__ A_re,
    const float* __restrict__ A_im, const float* __restrict__ C_re,
    const float* __restrict__ C_im, float* __restrict__ P)
{
    int i = blockIdx.x * 256 + threadIdx.x;
    if (i >= HN) return;
    int h = i >> 6;
    float dt = expf(log_dt[h]);
    float Ar = A_re[i], Ai = A_im[i];
    float ar = dt * Ar, ai = dt * Ai;
    float e = expf(ar);
    float wr = e * cosf(ai);
    float wi = e * sinf(ai);
    float em1r = wr - 1.0f, em1i = wi;
    float inv = 1.0f / fmaf(Ar, Ar, Ai * Ai);
    // (exp(dtA)-1)/A = em1 * conj(A) / |A|^2
    float qr = fmaf(em1r, Ar, em1i * Ai) * inv;
    float qi = fmaf(em1i, Ar, -(em1r * Ai)) * inv;
    float Cr = C_re[i], Ci = C_im[i];
    float ctr = Cr * qr - Ci * qi;
    float cti = Cr * qi + Ci * qr;
    P[i]          = wr;
    P[HN + i]     = wi;
    P[2 * HN + i] = 2.0f * ctr;
    P[3 * HN + i] = 2.0f * cti;
}

// ---------------------------------------------------------------------------
// 2) Transpose x (B,L,H) -> XT (B,H,L)
// ---------------------------------------------------------------------------
__global__ __launch_bounds__(256) void transpose_kernel(
    const float* __restrict__ x, float* __restrict__ XT)
{
    __shared__ float tile[32][33];
    int b  = blockIdx.z;
    int l0 = blockIdx.x * 32;
    int h0 = blockIdx.y * 32;
    int tx = threadIdx.x & 31;
    int ty = threadIdx.x >> 5; // 0..7
    #pragma unroll
    for (int r = 0; r < 4; ++r) {
        int lr = ty + r * 8;
        tile[lr][tx] = x[((size_t)b * L_DIM + l0 + lr) * H_DIM + h0 + tx];
    }
    __syncthreads();
    #pragma unroll
    for (int r = 0; r < 4; ++r) {
        int hr = ty + r * 8;
        XT[((size_t)b * H_DIM + h0 + hr) * L_DIM + l0 + tx] = tile[tx][hr];
    }
}

// ---------------------------------------------------------------------------
// 3) Diagonal-SSM scan. One wave per (b,h); lane = state index n (64 states).
//    s[l] = u[l] + w*s[l-1];  y[l] = sum_n Re(Ct2_n * s_n[l])
//    Reduction over n via per-64-step LDS transpose (stride 65 => 2-way, free).
//    Fused: + D*u skip, tanh-GELU. Output YT in (B,H,L), coalesced.
// ---------------------------------------------------------------------------
__global__ __launch_bounds__(128) void ssm_scan_kernel(
    const float* __restrict__ XT, const float* __restrict__ P,
    const float* __restrict__ D_skip, float* __restrict__ YT)
{
    __shared__ float ps[2][64 * 65];
    __shared__ float uc[2][64];
    const int w    = threadIdx.x >> 6;
    const int lane = threadIdx.x & 63;
    const int wid  = blockIdx.x * 2 + w;      // b*H + h
    const int h    = wid & (H_DIM - 1);
    const int pidx = h * 64 + lane;
    const float wr = P[pidx];
    const float wi = P[HN + pidx];
    const float cr = P[2 * HN + pidx];
    const float ci = P[3 * HN + pidx];
    const float Dh = D_skip[h];
    const float* u = XT + (size_t)wid * L_DIM;
    float* yo      = YT + (size_t)wid * L_DIM;
    float* psw = ps[w];
    float* ucw = uc[w];
    float sr = 0.0f, si = 0.0f;
    for (int l0 = 0; l0 < L_DIM; l0 += 64) {
        ucw[lane] = u[l0 + lane];
        __syncthreads();
        #pragma unroll 16
        for (int j = 0; j < 64; ++j) {
            float uv  = ucw[j];
            float t1  = fmaf(-wi, si, uv);
            float nsr = fmaf(wr, sr, t1);
            float nsi = fmaf(wr, si, wi * sr);
            sr = nsr; si = nsi;
            psw[lane * 65 + j] = fmaf(cr, sr, -(ci * si));
        }
        __syncthreads();
        float acc = 0.0f;
        #pragma unroll 16
        for (int n = 0; n < 64; ++n) acc += psw[n * 65 + lane];
        float yy = fmaf(Dh, ucw[lane], acc);
        yo[l0 + lane] = gelu_tanh_(yy);
        __syncthreads();
    }
}

// ---------------------------------------------------------------------------
// 4) GEMM1 + GLU + residual:
//    For m=(b,l), h: a = sum_k W[h,k]*Y[b,k,l]+b_out[h],
//                    g = sum_k W[512+h,k]*Y[b,k,l]+b_out[512+h]
//    x1p[m,h] = x[m,h] + a*sigmoid(g)
// ---------------------------------------------------------------------------
__global__ __launch_bounds__(256) void gemm1_glu_kernel(
    const float* __restrict__ YT, const float* __restrict__ W,
    const float* __restrict__ bvec, const float* __restrict__ xin,
    float* __restrict__ x1p)
{
    __shared__ float As[16][64];
    __shared__ float Ba[16][68];
    __shared__ float Bg[16][68];
    const int t  = threadIdx.x;
    const int m0 = blockIdx.x * 64;
    const int h0 = blockIdx.y * 64;
    const int b  = m0 >> 11;
    const int l0 = m0 & 2047;
    const int tx = t & 15;
    const int ty = t >> 4;
    const int ka = t >> 4;        // 0..15
    const int ma = (t & 15) * 4;
    const int nb = t >> 2;        // 0..63
    const int kb = (t & 3) * 4;
    const float* Yb = YT + (size_t)b * (H_DIM * L_DIM);
    float accA[4][4] = {{0.0f}};
    float accG[4][4] = {{0.0f}};
    for (int k0 = 0; k0 < 512; k0 += 16) {
        float4 av  = *(const float4*)(Yb + (size_t)(k0 + ka) * L_DIM + l0 + ma);
        float4 bva = *(const float4*)(W + (size_t)(h0 + nb) * 512 + k0 + kb);
        float4 bvg = *(const float4*)(W + (size_t)(512 + h0 + nb) * 512 + k0 + kb);
        __syncthreads();
        *(float4*)&As[ka][ma] = av;
        Ba[kb + 0][nb] = bva.x; Ba[kb + 1][nb] = bva.y;
        Ba[kb + 2][nb] = bva.z; Ba[kb + 3][nb] = bva.w;
        Bg[kb + 0][nb] = bvg.x; Bg[kb + 1][nb] = bvg.y;
        Bg[kb + 2][nb] = bvg.z; Bg[kb + 3][nb] = bvg.w;
        __syncthreads();
        #pragma unroll
        for (int k = 0; k < 16; ++k) {
            float a[4], ba[4], bg[4];
            *(float4*)a  = *(const float4*)&As[k][tx * 4];
            *(float4*)ba = *(const float4*)&Ba[k][ty * 4];
            *(float4*)bg = *(const float4*)&Bg[k][ty * 4];
            #pragma unroll
            for (int i = 0; i < 4; ++i) {
                #pragma unroll
                for (int j = 0; j < 4; ++j) {
                    accA[i][j] = fmaf(a[i], ba[j], accA[i][j]);
                    accG[i][j] = fmaf(a[i], bg[j], accG[i][j]);
                }
            }
        }
    }
    float biasA[4], biasG[4];
    #pragma unroll
    for (int j = 0; j < 4; ++j) {
        biasA[j] = bvec[h0 + ty * 4 + j];
        biasG[j] = bvec[512 + h0 + ty * 4 + j];
    }
    #pragma unroll
    for (int i = 0; i < 4; ++i) {
        size_t m   = (size_t)(m0 + tx * 4 + i);
        size_t off = m * 512 + h0 + ty * 4;
        float4 xv  = *(const float4*)(xin + off);
        const float* xf = (const float*)&xv;
        float o[4];
        #pragma unroll
        for (int j = 0; j < 4; ++j) {
            float aa = accA[i][j] + biasA[j];
            float gg = accG[i][j] + biasG[j];
            o[j] = xf[j] + aa * sigmoidf_(gg);
        }
        *(float4*)(x1p + off) = *(float4*)o;
    }
}

// ---------------------------------------------------------------------------
// 6/7) C = A(M x 512) * Bw(N x 512)^T + bias, optional ReLU
// ---------------------------------------------------------------------------
template<bool RELU>
__global__ __launch_bounds__(256) void gemm_bt_kernel(
    const float* __restrict__ A, const float* __restrict__ Bw,
    const float* __restrict__ bias, float* __restrict__ C)
{
    __shared__ float As[16][68];
    __shared__ float Bs[16][68];
    const int t  = threadIdx.x;
    const int m0 = blockIdx.x * 64;
    const int n0 = blockIdx.y * 64;
    const int tx = t & 15, ty = t >> 4;
    const int r  = t >> 2;        // 0..63
    const int kq = (t & 3) * 4;
    float acc[4][4] = {{0.0f}};
    for (int k0 = 0; k0 < 512; k0 += 16) {
        float4 a4 = *(const float4*)(A  + (size_t)(m0 + r) * 512 + k0 + kq);
        float4 b4 = *(const float4*)(Bw + (size_t)(n0 + r) * 512 + k0 + kq);
        __syncthreads();
        As[kq + 0][r] = a4.x; As[kq + 1][r] = a4.y;
        As[kq + 2][r] = a4.z; As[kq + 3][r] = a4.w;
        Bs[kq + 0][r] = b4.x; Bs[kq + 1][r] = b4.y;
        Bs[kq + 2][r] = b4.z; Bs[kq + 3][r] = b4.w;
        __syncthreads();
        #pragma unroll
        for (int k = 0; k < 16; ++k) {
            float a[4], bb[4];
            *(float4*)a  = *(const float4*)&As[k][tx * 4];
            *(float4*)bb = *(const float4*)&Bs[k][ty * 4];
            #pragma unroll
            for (int i = 0; i < 4; ++i) {
                #pragma unroll
                for (int j = 0; j < 4; ++j)
                    acc[i][j] = fmaf(a[i], bb[j], acc[i][j]);
            }
        }
    }
    float bv[4];
    #pragma unroll
    for (int j = 0; j < 4; ++j) bv[j] = bias[n0 + ty * 4 + j];
    #pragma unroll
    for (int i = 0; i < 4; ++i) {
        size_t off = (size_t)(m0 + tx * 4 + i) * 512 + n0 + ty * 4;
        float o[4];
        #pragma unroll
        for (int j = 0; j < 4; ++j) {
            float v = acc[i][j] + bv[j];
            if (RELU) v = fmaxf(v, 0.0f);
            o[j] = v;
        }
        *(float4*)(C + off) = *(float4*)o;
    }
}

// ---------------------------------------------------------------------------
// 5/8) LayerNorm over H=512 per row; optional residual add; in-place safe.
//      One wave per row, 4 rows per block.
// ---------------------------------------------------------------------------
__global__ __launch_bounds__(256) void ln_kernel(
    const float* __restrict__ in, const float* res,
    const float* __restrict__ gamma, const float* __restrict__ beta,
    float* out)
{
    int w    = threadIdx.x >> 6;
    int lane = threadIdx.x & 63;
    size_t row = (size_t)blockIdx.x * 4 + w;
    const float* ip = in + row * 512 + lane * 8;
    float v[8];
    *(float4*)&v[0] = *(const float4*)(ip);
    *(float4*)&v[4] = *(const float4*)(ip + 4);
    if (res != nullptr) {
        const float* rp = res + row * 512 + lane * 8;
        float rv[8];
        *(float4*)&rv[0] = *(const float4*)(rp);
        *(float4*)&rv[4] = *(const float4*)(rp + 4);
        #pragma unroll
        for (int i = 0; i < 8; ++i) v[i] += rv[i];
    }
    float s = 0.0f, sq = 0.0f;
    #pragma unroll
    for (int i = 0; i < 8; ++i) { s += v[i]; sq = fmaf(v[i], v[i], sq); }
    #pragma unroll
    for (int m = 32; m > 0; m >>= 1) {
        s  += __shfl_xor(s, m, 64);
        sq += __shfl_xor(sq, m, 64);
    }
    float mu  = s * (1.0f / 512.0f);
    float var = sq * (1.0f / 512.0f) - mu * mu;
    float rs  = rsqrtf(var + 1e-5f);
    float g[8], bt[8];
    *(float4*)&g[0]  = *(const float4*)(gamma + lane * 8);
    *(float4*)&g[4]  = *(const float4*)(gamma + lane * 8 + 4);
    *(float4*)&bt[0] = *(const float4*)(beta + lane * 8);
    *(float4*)&bt[4] = *(const float4*)(beta + lane * 8 + 4);
    float o[8];
    #pragma unroll
    for (int i = 0; i < 8; ++i)
        o[i] = fmaf((v[i] - mu) * rs, g[i], bt[i]);
    float* op = out + row * 512 + lane * 8;
    *(float4*)(op)     = *(float4*)&o[0];
    *(float4*)(op + 4) = *(float4*)&o[4];
}

// ---------------------------------------------------------------------------
extern "C" void kernel_launch(void* const* d_in, const int* in_sizes, int n_in,
                              void* d_out, int out_size, void* d_ws, size_t ws_size,
                              hipStream_t stream)
{
    (void)in_sizes; (void)n_in; (void)out_size; (void)ws_size;
    const float* x      = (const float*)d_in[0];
    const float* log_dt = (const float*)d_in[1];
    const float* A_re   = (const float*)d_in[2];
    const float* A_im   = (const float*)d_in[3];
    const float* C_re   = (const float*)d_in[4];
    const float* C_im   = (const float*)d_in[5];
    const float* D_skip = (const float*)d_in[6];
    const float* W_out  = (const float*)d_in[7];
    const float* b_out  = (const float*)d_in[8];
    const float* g1     = (const float*)d_in[9];
    const float* beta1  = (const float*)d_in[10];
    const float* g2     = (const float*)d_in[11];
    const float* beta2  = (const float*)d_in[12];
    const float* W1     = (const float*)d_in[13];
    const float* bc1    = (const float*)d_in[14];
    const float* W2     = (const float*)d_in[15];
    const float* bc2    = (const float*)d_in[16];
    float* out = (float*)d_out;

    // workspace layout: P (4*HN) | XT (BLH, later x1) | YT (BLH, later h1)
    float* P  = (float*)d_ws;
    float* XT = P + 4 * HN;
    float* YT = XT + BLH;

    precompute_kernel<<<HN / 256, 256, 0, stream>>>(log_dt, A_re, A_im, C_re, C_im, P);
    transpose_kernel<<<dim3(L_DIM / 32, H_DIM / 32, B_DIM), 256, 0, stream>>>(x, XT);
    ssm_scan_kernel<<<(B_DIM * H_DIM) / 2, 128, 0, stream>>>(XT, P, D_skip, YT);
    // x1p (pre-LN) overwrites XT (dead after scan)
    gemm1_glu_kernel<<<dim3(256, 8), 256, 0, stream>>>(YT, W_out, b_out, x, XT);
    ln_kernel<<<4096, 256, 0, stream>>>(XT, nullptr, g1, beta1, XT);
    // h1 overwrites YT (dead after gemm1)
    gemm_bt_kernel<true><<<dim3(256, 8), 256, 0, stream>>>(XT, W1, bc1, YT);
    gemm_bt_kernel<false><<<dim3(256, 8), 256, 0, stream>>>(YT, W2, bc2, out);
    ln_kernel<<<4096, 256, 0, stream>>>(XT, out, g2, beta2, out);
}

// Round 2
// 373.216 us; speedup vs baseline: 2.0546x; 2.0546x over previous
//
#include <hip/hip_runtime.h>
#include <cstddef>
#include <cstdint>

#define B_DIM 8
#define L_DIM 2048
#define H_DIM 512
#define N_DIM 64
#define HN (H_DIM * N_DIM)          // 32768
#define BLH (B_DIM * L_DIM * H_DIM) // 8388608
#define M_DIM (B_DIM * L_DIM)       // 16384

typedef unsigned short u16;
typedef short bf16x8 __attribute__((ext_vector_type(8)));   // 8 bf16 (guide-verified frag type)
typedef float floatx4 __attribute__((ext_vector_type(4)));

__device__ __forceinline__ float sigmoidf_(float v) {
    return 1.0f / (1.0f + __expf(-v));
}

// jax.nn.gelu default: approximate=True (tanh form)
__device__ __forceinline__ float gelu_tanh_(float x) {
    float x3 = x * x * x;
    float z = 0.7978845608028654f * fmaf(0.044715f, x3, x);
    float e = __expf(-2.0f * fabsf(z));
    float th = (1.0f - e) / (1.0f + e);
    th = copysignf(th, z);
    return 0.5f * x * (1.0f + th);
}

// fp32 -> bf16 round-to-nearest-even (manual, version-independent)
__device__ __forceinline__ u16 f2b(float f) {
    unsigned u = __float_as_uint(f);
    unsigned r = (u + 0x7fffu + ((u >> 16) & 1u)) >> 16;
    return (u16)r;
}
__device__ __forceinline__ float b2f(u16 u) {
    return __uint_as_float(((unsigned)u) << 16);
}
__device__ __forceinline__ void unpack2(unsigned u, float& a, float& b) {
    a = __uint_as_float(u << 16);
    b = __uint_as_float(u & 0xffff0000u);
}
__device__ __forceinline__ unsigned pack2(float a, float b) {
    return (unsigned)f2b(a) | ((unsigned)f2b(b) << 16);
}

// ---------------------------------------------------------------------------
// 0) fp32 -> bf16 cast (weights), 4 elems/thread
// ---------------------------------------------------------------------------
__global__ __launch_bounds__(256) void cast_kernel(
    const float* __restrict__ src, u16* __restrict__ dst)
{
    int i = blockIdx.x * 256 + threadIdx.x;
    float4 v = *(const float4*)(src + (size_t)i * 4);
    uint2 p;
    p.x = pack2(v.x, v.y);
    p.y = pack2(v.z, v.w);
    *(uint2*)(dst + (size_t)i * 4) = p;
}

// ---------------------------------------------------------------------------
// 1) Per-(h,n) SSM params: w = exp(dt*A), Ct2 = 2*C*(exp(dt*A)-1)/A
// ---------------------------------------------------------------------------
__global__ __launch_bounds__(256) void precompute_kernel(
    const float* __restrict__ log_dt, const float* __restrict__ A_re,
    const float* __restrict__ A_im, const float* __restrict__ C_re,
    const float* __restrict__ C_im, float* __restrict__ P)
{
    int i = blockIdx.x * 256 + threadIdx.x;
    if (i >= HN) return;
    int h = i >> 6;
    float dt = expf(log_dt[h]);
    float Ar = A_re[i], Ai = A_im[i];
    float ar = dt * Ar, ai = dt * Ai;
    float e = expf(ar);
    float wr = e * cosf(ai);
    float wi = e * sinf(ai);
    float em1r = wr - 1.0f, em1i = wi;
    float inv = 1.0f / fmaf(Ar, Ar, Ai * Ai);
    float qr = fmaf(em1r, Ar, em1i * Ai) * inv;
    float qi = fmaf(em1i, Ar, -(em1r * Ai)) * inv;
    float Cr = C_re[i], Ci = C_im[i];
    float ctr = Cr * qr - Ci * qi;
    float cti = Cr * qi + Ci * qr;
    P[i]          = wr;
    P[HN + i]     = wi;
    P[2 * HN + i] = 2.0f * ctr;
    P[3 * HN + i] = 2.0f * cti;
}

// ---------------------------------------------------------------------------
// 2) Transpose x (B,L,H) fp32 -> XT (B,H,L) bf16
// ---------------------------------------------------------------------------
__global__ __launch_bounds__(256) void xtrans_kernel(
    const float* __restrict__ x, u16* __restrict__ XT)
{
    __shared__ float tile[32][33];
    int b  = blockIdx.z;
    int l0 = blockIdx.x * 32;
    int h0 = blockIdx.y * 32;
    int tx = threadIdx.x & 31;
    int ty = threadIdx.x >> 5;
    #pragma unroll
    for (int r = 0; r < 4; ++r)
        tile[ty + r * 8][tx] = x[((size_t)b * L_DIM + l0 + ty + r * 8) * H_DIM + h0 + tx];
    __syncthreads();
    #pragma unroll
    for (int r = 0; r < 4; ++r)
        XT[((size_t)b * H_DIM + h0 + ty + r * 8) * L_DIM + l0 + tx] = f2b(tile[tx][ty + r * 8]);
}

// ---------------------------------------------------------------------------
// 3) Diagonal-SSM scan. One wave per (b,h); lane = state n.
//    u broadcast via v_readlane (no LDS); partials in [j][n] layout pitch 68
//    so reduction reads are ds_read_b128 (16 per 64 steps).
// ---------------------------------------------------------------------------
__global__ __launch_bounds__(128) void ssm_scan_kernel(
    const u16* __restrict__ XT, const float* __restrict__ P,
    const float* __restrict__ D_skip, u16* __restrict__ YT)
{
    __shared__ __align__(16) float ps[2][64 * 68];
    const int w    = threadIdx.x >> 6;
    const int lane = threadIdx.x & 63;
    const int wid  = blockIdx.x * 2 + w;      // b*H + h
    const int h    = wid & (H_DIM - 1);
    const int pidx = h * 64 + lane;
    const float wr = P[pidx];
    const float wi = P[HN + pidx];
    const float cr = P[2 * HN + pidx];
    const float ci = P[3 * HN + pidx];
    const float Dh = D_skip[h];
    const u16* u = XT + (size_t)wid * L_DIM;
    u16* yo      = YT + (size_t)wid * L_DIM;
    float* psw = ps[w];
    float sr = 0.0f, si = 0.0f;
    for (int l0 = 0; l0 < L_DIM; l0 += 64) {
        float uv_l = b2f(u[l0 + lane]);
        int ubits = __float_as_int(uv_l);
        #pragma unroll
        for (int j = 0; j < 64; ++j) {
            float uv  = __int_as_float(__builtin_amdgcn_readlane(ubits, j));
            float t1  = fmaf(-wi, si, uv);
            float nsr = fmaf(wr, sr, t1);
            float nsi = fmaf(wr, si, wi * sr);
            sr = nsr; si = nsi;
            psw[j * 68 + lane] = fmaf(cr, sr, -(ci * si));
        }
        __syncthreads();
        float acc = 0.0f;
        #pragma unroll
        for (int tt = 0; tt < 16; ++tt) {
            float4 pv = *(const float4*)&psw[lane * 68 + tt * 4];
            acc += (pv.x + pv.y) + (pv.z + pv.w);
        }
        float yy = fmaf(Dh, uv_l, acc);
        yo[l0 + lane] = f2b(gelu_tanh_(yy));
        __syncthreads();
    }
}

// ---------------------------------------------------------------------------
// 4) Transpose YT (B,H,L) bf16 -> Y (B,L,H) bf16
// ---------------------------------------------------------------------------
__global__ __launch_bounds__(256) void ytrans_kernel(
    const u16* __restrict__ YT, u16* __restrict__ Y)
{
    __shared__ u16 tile[32][33];
    int b  = blockIdx.z;
    int l0 = blockIdx.x * 32;
    int h0 = blockIdx.y * 32;
    int tx = threadIdx.x & 31;
    int ty = threadIdx.x >> 5;
    #pragma unroll
    for (int r = 0; r < 4; ++r)
        tile[ty + r * 8][tx] = YT[((size_t)b * H_DIM + h0 + ty + r * 8) * L_DIM + l0 + tx];
    __syncthreads();
    #pragma unroll
    for (int r = 0; r < 4; ++r)
        Y[((size_t)b * L_DIM + l0 + ty + r * 8) * H_DIM + h0 + tx] = tile[tx][ty + r * 8];
}

// ---------------------------------------------------------------------------
// MFMA GEMM machinery: stage a 128x32 bf16 tile (row-major, ld=512) into LDS
// via global_load_lds width=16. LDS layout dense [128][32].
// ---------------------------------------------------------------------------
__device__ __forceinline__ void stage_tile_128x32(
    const u16* __restrict__ g, u16* lds, int row0, int k0)
{
    const int t = threadIdx.x;
    #pragma unroll
    for (int r = 0; r < 2; ++r) {
        int row = (t >> 2) + r * 64;
        int col = (t & 3) * 8;
        const u16* gp = g + (size_t)(row0 + row) * 512 + k0 + col;
        __builtin_amdgcn_global_load_lds(
            (const __attribute__((address_space(1))) unsigned int*)gp,
            (__attribute__((address_space(3))) unsigned int*)(lds + (size_t)t * 8 + (size_t)r * 2048),
            16, 0, 0);
    }
}

// ---------------------------------------------------------------------------
// 5) GEMM1 + GLU + residual (dual-B): out_bf16[m,n] = x[m,n] + a*sigmoid(g)
//    a = Y[m,:]·Wo[n,:] + bo[n],  g = Y[m,:]·Wo[512+n,:] + bo[512+n]
// ---------------------------------------------------------------------------
__global__ __launch_bounds__(256) void gemm1_glu_kernel(
    const u16* __restrict__ A, const u16* __restrict__ Wo,
    const float* __restrict__ bo, const float* __restrict__ x,
    u16* __restrict__ out)
{
    __shared__ u16 As[128 * 32];
    __shared__ u16 Ba[128 * 32];
    __shared__ u16 Bg[128 * 32];
    const int t    = threadIdx.x;
    const int lane = t & 63;
    const int wv   = t >> 6;
    const int wm   = wv >> 1, wn = wv & 1;
    const int lm   = lane & 15, lq = lane >> 4;
    const int m0   = blockIdx.x * 128, n0 = blockIdx.y * 128;
    floatx4 accA[4][4] = {};
    floatx4 accG[4][4] = {};
    for (int k0 = 0; k0 < 512; k0 += 32) {
        stage_tile_128x32(A, As, m0, k0);
        stage_tile_128x32(Wo, Ba, n0, k0);
        stage_tile_128x32(Wo, Bg, 512 + n0, k0);
        __syncthreads();
        bf16x8 af[4], ba[4], bg[4];
        #pragma unroll
        for (int i = 0; i < 4; ++i)
            af[i] = *(const bf16x8*)&As[(wm * 64 + i * 16 + lm) * 32 + lq * 8];
        #pragma unroll
        for (int j = 0; j < 4; ++j) {
            ba[j] = *(const bf16x8*)&Ba[(wn * 64 + j * 16 + lm) * 32 + lq * 8];
            bg[j] = *(const bf16x8*)&Bg[(wn * 64 + j * 16 + lm) * 32 + lq * 8];
        }
        #pragma unroll
        for (int i = 0; i < 4; ++i) {
            #pragma unroll
            for (int j = 0; j < 4; ++j) {
                accA[i][j] = __builtin_amdgcn_mfma_f32_16x16x32_bf16(af[i], ba[j], accA[i][j], 0, 0, 0);
                accG[i][j] = __builtin_amdgcn_mfma_f32_16x16x32_bf16(af[i], bg[j], accG[i][j], 0, 0, 0);
            }
        }
        __syncthreads();
    }
    #pragma unroll
    for (int j = 0; j < 4; ++j) {
        int n = n0 + wn * 64 + j * 16 + lm;
        float bav = bo[n], bgv = bo[512 + n];
        #pragma unroll
        for (int i = 0; i < 4; ++i) {
            #pragma unroll
            for (int r = 0; r < 4; ++r) {
                int m = m0 + wm * 64 + i * 16 + lq * 4 + r;
                float av = accA[i][j][r] + bav;
                float gv = accG[i][j][r] + bgv;
                float xv = x[(size_t)m * 512 + n];
                out[(size_t)m * 512 + n] = f2b(fmaf(av, sigmoidf_(gv), xv));
            }
        }
    }
}

// ---------------------------------------------------------------------------
// 6/7) MFMA GEMM: C_bf16 = act(A[M,512]·Bw[512,512]^T + bias). EPI: 1=relu
// ---------------------------------------------------------------------------
template<int EPI>
__global__ __launch_bounds__(256) void gemm_bt_bf_kernel(
    const u16* __restrict__ A, const u16* __restrict__ Bw,
    const float* __restrict__ bias, u16* __restrict__ C)
{
    __shared__ u16 As[128 * 32];
    __shared__ u16 Bs[128 * 32];
    const int t    = threadIdx.x;
    const int lane = t & 63;
    const int wv   = t >> 6;
    const int wm   = wv >> 1, wn = wv & 1;
    const int lm   = lane & 15, lq = lane >> 4;
    const int m0   = blockIdx.x * 128, n0 = blockIdx.y * 128;
    floatx4 acc[4][4] = {};
    for (int k0 = 0; k0 < 512; k0 += 32) {
        stage_tile_128x32(A, As, m0, k0);
        stage_tile_128x32(Bw, Bs, n0, k0);
        __syncthreads();
        bf16x8 af[4], bfr[4];
        #pragma unroll
        for (int i = 0; i < 4; ++i)
            af[i] = *(const bf16x8*)&As[(wm * 64 + i * 16 + lm) * 32 + lq * 8];
        #pragma unroll
        for (int j = 0; j < 4; ++j)
            bfr[j] = *(const bf16x8*)&Bs[(wn * 64 + j * 16 + lm) * 32 + lq * 8];
        #pragma unroll
        for (int i = 0; i < 4; ++i) {
            #pragma unroll
            for (int j = 0; j < 4; ++j)
                acc[i][j] = __builtin_amdgcn_mfma_f32_16x16x32_bf16(af[i], bfr[j], acc[i][j], 0, 0, 0);
        }
        __syncthreads();
    }
    #pragma unroll
    for (int j = 0; j < 4; ++j) {
        int n = n0 + wn * 64 + j * 16 + lm;
        float bv = bias[n];
        #pragma unroll
        for (int i = 0; i < 4; ++i) {
            #pragma unroll
            for (int r = 0; r < 4; ++r) {
                int m = m0 + wm * 64 + i * 16 + lq * 4 + r;
                float v = acc[i][j][r] + bv;
                if (EPI == 1) v = fmaxf(v, 0.0f);
                C[(size_t)m * 512 + n] = f2b(v);
            }
        }
    }
}

// ---------------------------------------------------------------------------
// 8) LayerNorm over H=512; bf16 in, optional bf16 residual; out bf16 or fp32
// ---------------------------------------------------------------------------
template<bool HASRES, bool F32OUT>
__global__ __launch_bounds__(256) void ln_bf_kernel(
    const u16* __restrict__ in, const u16* __restrict__ res,
    const float* __restrict__ gamma, const float* __restrict__ beta,
    u16* __restrict__ outb, float* __restrict__ outf)
{
    int w    = threadIdx.x >> 6;
    int lane = threadIdx.x & 63;
    size_t row  = (size_t)blockIdx.x * 4 + w;
    size_t base = row * 512 + lane * 8;
    uint4 raw = *(const uint4*)(in + base);
    float v[8];
    unpack2(raw.x, v[0], v[1]); unpack2(raw.y, v[2], v[3]);
    unpack2(raw.z, v[4], v[5]); unpack2(raw.w, v[6], v[7]);
    if (HASRES) {
        uint4 rr = *(const uint4*)(res + base);
        float rv[8];
        unpack2(rr.x, rv[0], rv[1]); unpack2(rr.y, rv[2], rv[3]);
        unpack2(rr.z, rv[4], rv[5]); unpack2(rr.w, rv[6], rv[7]);
        #pragma unroll
        for (int i = 0; i < 8; ++i) v[i] += rv[i];
    }
    float s = 0.0f, sq = 0.0f;
    #pragma unroll
    for (int i = 0; i < 8; ++i) { s += v[i]; sq = fmaf(v[i], v[i], sq); }
    #pragma unroll
    for (int m = 32; m > 0; m >>= 1) {
        s  += __shfl_xor(s, m, 64);
        sq += __shfl_xor(sq, m, 64);
    }
    float mu  = s * (1.0f / 512.0f);
    float var = sq * (1.0f / 512.0f) - mu * mu;
    float rs  = rsqrtf(var + 1e-5f);
    float g[8], bt[8];
    *(float4*)&g[0]  = *(const float4*)(gamma + lane * 8);
    *(float4*)&g[4]  = *(const float4*)(gamma + lane * 8 + 4);
    *(float4*)&bt[0] = *(const float4*)(beta + lane * 8);
    *(float4*)&bt[4] = *(const float4*)(beta + lane * 8 + 4);
    float o[8];
    #pragma unroll
    for (int i = 0; i < 8; ++i)
        o[i] = fmaf((v[i] - mu) * rs, g[i], bt[i]);
    if (F32OUT) {
        *(float4*)(outf + base)     = *(float4*)&o[0];
        *(float4*)(outf + base + 4) = *(float4*)&o[4];
    } else {
        uint4 p;
        p.x = pack2(o[0], o[1]); p.y = pack2(o[2], o[3]);
        p.z = pack2(o[4], o[5]); p.w = pack2(o[6], o[7]);
        *(uint4*)(outb + base) = p;
    }
}

// ---------------------------------------------------------------------------
extern "C" void kernel_launch(void* const* d_in, const int* in_sizes, int n_in,
                              void* d_out, int out_size, void* d_ws, size_t ws_size,
                              hipStream_t stream)
{
    (void)in_sizes; (void)n_in; (void)out_size; (void)ws_size;
    const float* x      = (const float*)d_in[0];
    const float* log_dt = (const float*)d_in[1];
    const float* A_re   = (const float*)d_in[2];
    const float* A_im   = (const float*)d_in[3];
    const float* C_re   = (const float*)d_in[4];
    const float* C_im   = (const float*)d_in[5];
    const float* D_skip = (const float*)d_in[6];
    const float* W_out  = (const float*)d_in[7];
    const float* b_out  = (const float*)d_in[8];
    const float* g1     = (const float*)d_in[9];
    const float* beta1  = (const float*)d_in[10];
    const float* g2     = (const float*)d_in[11];
    const float* beta2  = (const float*)d_in[12];
    const float* W1     = (const float*)d_in[13];
    const float* bc1    = (const float*)d_in[14];
    const float* W2     = (const float*)d_in[15];
    const float* bc2    = (const float*)d_in[16];
    float* out = (float*)d_out;

    // workspace: P (512KB) | Wbf (2MB) | r1 | r2 | r3 (bf16 BLH each) = ~53MB
    char* wsb   = (char*)d_ws;
    float* P    = (float*)wsb;
    u16*  Wobf  = (u16*)(wsb + 4 * HN * 4);
    u16*  W1bf  = Wobf + 1024 * 512;
    u16*  W2bf  = W1bf + 512 * 512;
    u16*  r1    = W2bf + 512 * 512;   // XTbf -> x1n_bf
    u16*  r2    = r1 + BLH;           // YTbf -> x1pre_bf -> y2_bf
    u16*  r3    = r2 + BLH;           // Ybf  -> h1_bf

    cast_kernel<<<512, 256, 0, stream>>>(W_out, Wobf);
    cast_kernel<<<256, 256, 0, stream>>>(W1, W1bf);
    cast_kernel<<<256, 256, 0, stream>>>(W2, W2bf);
    precompute_kernel<<<HN / 256, 256, 0, stream>>>(log_dt, A_re, A_im, C_re, C_im, P);
    xtrans_kernel<<<dim3(L_DIM / 32, H_DIM / 32, B_DIM), 256, 0, stream>>>(x, r1);
    ssm_scan_kernel<<<(B_DIM * H_DIM) / 2, 128, 0, stream>>>(r1, P, D_skip, r2);
    ytrans_kernel<<<dim3(L_DIM / 32, H_DIM / 32, B_DIM), 256, 0, stream>>>(r2, r3);
    gemm1_glu_kernel<<<dim3(M_DIM / 128, 4), 256, 0, stream>>>(r3, Wobf, b_out, x, r2);
    ln_bf_kernel<false, false><<<M_DIM / 4, 256, 0, stream>>>(r2, nullptr, g1, beta1, r1, nullptr);
    gemm_bt_bf_kernel<1><<<dim3(M_DIM / 128, 4), 256, 0, stream>>>(r1, W1bf, bc1, r3);
    gemm_bt_bf_kernel<0><<<dim3(M_DIM / 128, 4), 256, 0, stream>>>(r3, W2bf, bc2, r2);
    ln_bf_kernel<true, true><<<M_DIM / 4, 256, 0, stream>>>(r2, r1, g2, beta2, nullptr, out);
}

// Round 3
// 268.501 us; speedup vs baseline: 2.8558x; 1.3900x over previous
//
#include <hip/hip_runtime.h>
#include <cstddef>
#include <cstdint>

#define B_DIM 8
#define L_DIM 2048
#define H_DIM 512
#define N_DIM 64
#define HN (H_DIM * N_DIM)          // 32768
#define BLH (B_DIM * L_DIM * H_DIM) // 8388608
#define M_DIM (B_DIM * L_DIM)       // 16384

typedef unsigned short u16;
typedef short bf16x8 __attribute__((ext_vector_type(8)));
typedef float floatx4 __attribute__((ext_vector_type(4)));

__device__ __forceinline__ float sigmoidf_(float v) {
    return 1.0f / (1.0f + __expf(-v));
}

// jax.nn.gelu default: approximate=True (tanh form)
__device__ __forceinline__ float gelu_tanh_(float x) {
    float x3 = x * x * x;
    float z = 0.7978845608028654f * fmaf(0.044715f, x3, x);
    float e = __expf(-2.0f * fabsf(z));
    float th = (1.0f - e) / (1.0f + e);
    th = copysignf(th, z);
    return 0.5f * x * (1.0f + th);
}

__device__ __forceinline__ u16 f2b(float f) {
    unsigned u = __float_as_uint(f);
    unsigned r = (u + 0x7fffu + ((u >> 16) & 1u)) >> 16;
    return (u16)r;
}
__device__ __forceinline__ float b2f(u16 u) {
    return __uint_as_float(((unsigned)u) << 16);
}
__device__ __forceinline__ void unpack2(unsigned u, float& a, float& b) {
    a = __uint_as_float(u << 16);
    b = __uint_as_float(u & 0xffff0000u);
}
__device__ __forceinline__ unsigned pack2(float a, float b) {
    return (unsigned)f2b(a) | ((unsigned)f2b(b) << 16);
}

// complex helpers
__device__ __forceinline__ void csq(float& r, float& i) {
    float nr = r * r - i * i;
    i = 2.0f * r * i;
    r = nr;
}

// ---------------------------------------------------------------------------
// 0) fp32 -> bf16 cast (weights)
// ---------------------------------------------------------------------------
__global__ __launch_bounds__(256) void cast_kernel(
    const float* __restrict__ src, u16* __restrict__ dst)
{
    int i = blockIdx.x * 256 + threadIdx.x;
    float4 v = *(const float4*)(src + (size_t)i * 4);
    uint2 p;
    p.x = pack2(v.x, v.y);
    p.y = pack2(v.z, v.w);
    *(uint2*)(dst + (size_t)i * 4) = p;
}

// ---------------------------------------------------------------------------
// 1) Per-(h,n) SSM params: w = exp(dt*A), Ct2 = 2*C*(exp(dt*A)-1)/A
// ---------------------------------------------------------------------------
__global__ __launch_bounds__(256) void precompute_kernel(
    const float* __restrict__ log_dt, const float* __restrict__ A_re,
    const float* __restrict__ A_im, const float* __restrict__ C_re,
    const float* __restrict__ C_im, float* __restrict__ P)
{
    int i = blockIdx.x * 256 + threadIdx.x;
    if (i >= HN) return;
    int h = i >> 6;
    float dt = expf(log_dt[h]);
    float Ar = A_re[i], Ai = A_im[i];
    float ar = dt * Ar, ai = dt * Ai;
    float e = expf(ar);
    float wr = e * cosf(ai);
    float wi = e * sinf(ai);
    float em1r = wr - 1.0f, em1i = wi;
    float inv = 1.0f / fmaf(Ar, Ar, Ai * Ai);
    float qr = fmaf(em1r, Ar, em1i * Ai) * inv;
    float qi = fmaf(em1i, Ar, -(em1r * Ai)) * inv;
    float Cr = C_re[i], Ci = C_im[i];
    float ctr = Cr * qr - Ci * qi;
    float cti = Cr * qi + Ci * qr;
    P[i]          = wr;
    P[HN + i]     = wi;
    P[2 * HN + i] = 2.0f * ctr;
    P[3 * HN + i] = 2.0f * cti;
}

// ---------------------------------------------------------------------------
// 1b) K table: K[h][tau] = sum_n Re(Ct2_n * w_n^tau), tau = 0..63
// ---------------------------------------------------------------------------
__global__ __launch_bounds__(256) void ktab_kernel(
    const float* __restrict__ P, float* __restrict__ Ktab)
{
    int wv = threadIdx.x >> 6, lane = threadIdx.x & 63;
    int h = blockIdx.x * 4 + wv;
    int pidx = (h << 6) + lane;
    float wr = P[pidx], wi = P[HN + pidx];
    float c2r = P[2 * HN + pidx], c2i = P[3 * HN + pidx];
    float pr = 1.0f, pi = 0.0f;
    for (int tau = 0; tau < 64; ++tau) {
        float term = c2r * pr - c2i * pi;
        #pragma unroll
        for (int m = 32; m > 0; m >>= 1) term += __shfl_xor(term, m, 64);
        if (lane == 0) Ktab[(h << 6) + tau] = term;
        float nr = pr * wr - pi * wi, ni = pr * wi + pi * wr;
        pr = nr; pi = ni;
    }
}

// ---------------------------------------------------------------------------
// 1c) Toeplitz fill: Toep_bf[h][t][j] = (j<=t) ? bf16(K[h][t-j]) : 0
// ---------------------------------------------------------------------------
__global__ __launch_bounds__(256) void toepfill_kernel(
    const float* __restrict__ Ktab, u16* __restrict__ Toep_bf)
{
    int idx = blockIdx.x * 256 + threadIdx.x;   // 512*4096
    int h = idx >> 12;
    int rem = idx & 4095;
    int tt = rem >> 6, j = rem & 63;
    u16 v = 0;
    if (j <= tt) v = f2b(Ktab[(h << 6) + (tt - j)]);
    Toep_bf[idx] = v;
}

// ---------------------------------------------------------------------------
// 2) Transpose x (B,L,H) fp32 -> XT (B,H,L) bf16
// ---------------------------------------------------------------------------
__global__ __launch_bounds__(256) void xtrans_kernel(
    const float* __restrict__ x, u16* __restrict__ XT)
{
    __shared__ float tile[32][33];
    int b  = blockIdx.z;
    int l0 = blockIdx.x * 32;
    int h0 = blockIdx.y * 32;
    int tx = threadIdx.x & 31;
    int ty = threadIdx.x >> 5;
    #pragma unroll
    for (int r = 0; r < 4; ++r)
        tile[ty + r * 8][tx] = x[((size_t)b * L_DIM + l0 + ty + r * 8) * H_DIM + h0 + tx];
    __syncthreads();
    #pragma unroll
    for (int r = 0; r < 4; ++r)
        XT[((size_t)b * H_DIM + h0 + ty + r * 8) * L_DIM + l0 + tx] = f2b(tile[tx][ty + r * 8]);
}

// ---------------------------------------------------------------------------
// 3) Chunked SSM via MFMA. One workgroup = (h, half of b). T=64, 32 chunks.
//    Phase A: S_local(128x128) = E(128x64) @ U(cols)  [MFMA]
//    Phase B: 32-step chunk recurrence (256 serial lanes)
//    Phase C: Y(64x128) = Toep(64x64)@U + V(64x128)@S_in [MFMA] + D*u + GELU
// ---------------------------------------------------------------------------
__global__ __launch_bounds__(256) void ssm_chunk_kernel(
    const u16* __restrict__ XT, const float* __restrict__ P,
    const u16* __restrict__ Toep_bf, const float* __restrict__ D_skip,
    u16* __restrict__ YT)
{
    __shared__ u16 U[128 * 72];      // [ncol][j], pad 72
    __shared__ u16 S[128 * 136];     // [ncol][2n], pad 136
    __shared__ u16 EVT[13312];       // union: E[128*72]=9216 | Toep[64*72]=4608 + V[64*136]=8704
    u16* E  = EVT;
    u16* Tp = EVT;
    u16* V  = EVT + 4608;

    const int h    = blockIdx.x;
    const int b0   = blockIdx.y * 4;
    const int t    = threadIdx.x;
    const int lane = t & 63;
    const int wv   = t >> 6;
    const int lm   = lane & 15, lq = lane >> 4;

    const int pidx = (h << 6) + lane;
    const float wr  = P[pidx],          wi  = P[HN + pidx];
    const float c2r = P[2 * HN + pidx], c2i = P[3 * HN + pidx];

    // stage U: 128 rows x 64 bf16, 16B chunks (coalesced), padded LDS rows
    #pragma unroll
    for (int r = 0; r < 4; ++r) {
        int idx = t + r * 256;
        int row = idx >> 3, ch = idx & 7;
        const u16* gp = XT + (((size_t)(b0 + (row >> 5)) * H_DIM + h) << 11)
                           + ((row & 31) << 6) + (ch << 3);
        *(uint4*)&U[row * 72 + ch * 8] = *(const uint4*)gp;
    }

    // base power w^(16*wv) for this wave
    float bwr, bwi;
    {
        float g16r = wr, g16i = wi;
        csq(g16r, g16i); csq(g16r, g16i); csq(g16r, g16i); csq(g16r, g16i); // w^16
        if (wv == 0)      { bwr = 1.0f; bwi = 0.0f; }
        else if (wv == 1) { bwr = g16r; bwi = g16i; }
        else if (wv == 2) { bwr = g16r; bwi = g16i; csq(bwr, bwi); }
        else {
            float g32r = g16r, g32i = g16i; csq(g32r, g32i);
            bwr = g32r * g16r - g32i * g16i;
            bwi = g32r * g16i + g32i * g16r;
        }
    }

    // fill E: E[2n][j]=Re(w^(63-j)), E[2n+1][j]=Im(w^(63-j)); wave wv covers k=16wv..16wv+15
    {
        float pr = bwr, pi = bwi;
        #pragma unroll
        for (int jk = 0; jk < 16; ++jk) {
            int k = (wv << 4) + jk;
            int j = 63 - k;
            E[(2 * lane) * 72 + j]     = f2b(pr);
            E[(2 * lane + 1) * 72 + j] = f2b(pi);
            float nr = pr * wr - pi * wi, ni = pr * wi + pi * wr;
            pr = nr; pi = ni;
        }
    }
    __syncthreads();

    // Phase A: acc[m][ncol], m = state index (2n interleaved), ncol = (bloc,c)
    {
        const int wm = wv >> 1, wn = wv & 1;
        floatx4 acc[4][4] = {};
        #pragma unroll
        for (int ks = 0; ks < 2; ++ks) {
            bf16x8 af[4], bfv[4];
            #pragma unroll
            for (int i = 0; i < 4; ++i)
                af[i] = *(const bf16x8*)&E[(wm * 64 + i * 16 + lm) * 72 + ks * 32 + lq * 8];
            #pragma unroll
            for (int j = 0; j < 4; ++j)
                bfv[j] = *(const bf16x8*)&U[(wn * 64 + j * 16 + lm) * 72 + ks * 32 + lq * 8];
            #pragma unroll
            for (int i = 0; i < 4; ++i) {
                #pragma unroll
                for (int j = 0; j < 4; ++j)
                    acc[i][j] = __builtin_amdgcn_mfma_f32_16x16x32_bf16(af[i], bfv[j], acc[i][j], 0, 0, 0);
            }
        }
        #pragma unroll
        for (int i = 0; i < 4; ++i) {
            #pragma unroll
            for (int j = 0; j < 4; ++j) {
                int ncol = wn * 64 + j * 16 + lm;
                int m0   = wm * 64 + i * 16 + lq * 4;
                u16 pk[4];
                #pragma unroll
                for (int r = 0; r < 4; ++r) pk[r] = f2b(acc[i][j][r]);
                *(uint2*)&S[ncol * 136 + m0] = *(uint2*)pk;
            }
        }
    }
    __syncthreads();   // E reads + S_local writes complete

    // fill V (overwrites E region, disjoint from Toep) + stage Toep + chunk scan
    {
        // V: wave wv covers k = 16wv+1 .. 16wv+16; V[t=k-1][2n]=Re(Ct2 w^k), [2n+1]=-Im
        float pr = bwr, pi = bwi;
        {   // advance to k = 16wv+1
            float nr = pr * wr - pi * wi, ni = pr * wi + pi * wr;
            pr = nr; pi = ni;
        }
        #pragma unroll
        for (int jk = 1; jk <= 16; ++jk) {
            int tr = (wv << 4) + jk - 1;
            float qr = c2r * pr - c2i * pi;
            float qi = c2r * pi + c2i * pr;
            V[tr * 136 + 2 * lane]     = f2b(qr);
            V[tr * 136 + 2 * lane + 1] = f2b(-qi);
            float nr = pr * wr - pi * wi, ni = pr * wi + pi * wr;
            pr = nr; pi = ni;
        }
        // stage Toeplitz 64x64 -> [64][72]
        #pragma unroll
        for (int r = 0; r < 2; ++r) {
            int idx = t + r * 256;
            int row = idx >> 3, ch = idx & 7;
            *(uint4*)&Tp[row * 72 + ch * 8] =
                *(const uint4*)&Toep_bf[((size_t)h << 12) + (row << 6) + (ch << 3)];
        }
        // chunk scan: thread = chain (bloc = wv, n = lane); in-place S_local -> S_in
        float wTr = wr, wTi = wi;
        csq(wTr, wTi); csq(wTr, wTi); csq(wTr, wTi);
        csq(wTr, wTi); csq(wTr, wTi); csq(wTr, wTi);   // w^64
        float Sr = 0.0f, Si = 0.0f;
        const int n2 = lane * 2;
        for (int c = 0; c < 32; ++c) {
            int base = (wv * 32 + c) * 136 + n2;
            unsigned lv = *(unsigned*)&S[base];
            float lr, li;
            unpack2(lv, lr, li);
            *(unsigned*)&S[base] = pack2(Sr, Si);
            float nSr = wTr * Sr - wTi * Si + lr;
            Si = wTr * Si + wTi * Sr + li;
            Sr = nSr;
        }
    }
    __syncthreads();

    // Phase C: Y[t][ncol] = Toep@U + V@S_in; epilogue D*u + GELU -> YT (b,h,l)
    {
        const float Dh = D_skip[h];
        floatx4 acc[4][2] = {};
        #pragma unroll
        for (int ks = 0; ks < 6; ++ks) {
            bf16x8 af[4], bfv[2];
            if (ks < 2) {
                #pragma unroll
                for (int i = 0; i < 4; ++i)
                    af[i] = *(const bf16x8*)&Tp[(i * 16 + lm) * 72 + ks * 32 + lq * 8];
                #pragma unroll
                for (int j = 0; j < 2; ++j)
                    bfv[j] = *(const bf16x8*)&U[(wv * 32 + j * 16 + lm) * 72 + ks * 32 + lq * 8];
            } else {
                #pragma unroll
                for (int i = 0; i < 4; ++i)
                    af[i] = *(const bf16x8*)&V[(i * 16 + lm) * 136 + (ks - 2) * 32 + lq * 8];
                #pragma unroll
                for (int j = 0; j < 2; ++j)
                    bfv[j] = *(const bf16x8*)&S[(wv * 32 + j * 16 + lm) * 136 + (ks - 2) * 32 + lq * 8];
            }
            #pragma unroll
            for (int i = 0; i < 4; ++i) {
                #pragma unroll
                for (int j = 0; j < 2; ++j)
                    acc[i][j] = __builtin_amdgcn_mfma_f32_16x16x32_bf16(af[i], bfv[j], acc[i][j], 0, 0, 0);
            }
        }
        #pragma unroll
        for (int j = 0; j < 2; ++j) {
            int ncol = wv * 32 + j * 16 + lm;
            int bloc = ncol >> 5, c = ncol & 31;
            size_t gbase = (((size_t)(b0 + bloc) * H_DIM + h) << 11) + (c << 6);
            #pragma unroll
            for (int i = 0; i < 4; ++i) {
                int t0 = i * 16 + lq * 4;
                u16 upk[4];
                *(uint2*)upk = *(const uint2*)&U[ncol * 72 + t0];
                u16 opk[4];
                #pragma unroll
                for (int r = 0; r < 4; ++r) {
                    float uvv = b2f(upk[r]);
                    float yv = gelu_tanh_(fmaf(Dh, uvv, acc[i][j][r]));
                    opk[r] = f2b(yv);
                }
                *(uint2*)&YT[gbase + t0] = *(uint2*)opk;
            }
        }
    }
}

// ---------------------------------------------------------------------------
// 4) Transpose YT (B,H,L) bf16 -> Y (B,L,H) bf16
// ---------------------------------------------------------------------------
__global__ __launch_bounds__(256) void ytrans_kernel(
    const u16* __restrict__ YT, u16* __restrict__ Y)
{
    __shared__ u16 tile[32][33];
    int b  = blockIdx.z;
    int l0 = blockIdx.x * 32;
    int h0 = blockIdx.y * 32;
    int tx = threadIdx.x & 31;
    int ty = threadIdx.x >> 5;
    #pragma unroll
    for (int r = 0; r < 4; ++r)
        tile[ty + r * 8][tx] = YT[((size_t)b * H_DIM + h0 + ty + r * 8) * L_DIM + l0 + tx];
    __syncthreads();
    #pragma unroll
    for (int r = 0; r < 4; ++r)
        Y[((size_t)b * L_DIM + l0 + ty + r * 8) * H_DIM + h0 + tx] = tile[tx][ty + r * 8];
}

// ---------------------------------------------------------------------------
// stage a 128x32 bf16 tile (row-major, ld=512) into LDS via global_load_lds
// ---------------------------------------------------------------------------
__device__ __forceinline__ void stage_tile_128x32(
    const u16* __restrict__ g, u16* lds, int row0, int k0)
{
    const int t = threadIdx.x;
    #pragma unroll
    for (int r = 0; r < 2; ++r) {
        int row = (t >> 2) + r * 64;
        int col = (t & 3) * 8;
        const u16* gp = g + (size_t)(row0 + row) * 512 + k0 + col;
        __builtin_amdgcn_global_load_lds(
            (const __attribute__((address_space(1))) unsigned int*)gp,
            (__attribute__((address_space(3))) unsigned int*)(lds + (size_t)t * 8 + (size_t)r * 2048),
            16, 0, 0);
    }
}

// ---------------------------------------------------------------------------
// 5) GEMM1 + GLU + residual (dual-B)
// ---------------------------------------------------------------------------
__global__ __launch_bounds__(256) void gemm1_glu_kernel(
    const u16* __restrict__ A, const u16* __restrict__ Wo,
    const float* __restrict__ bo, const float* __restrict__ x,
    u16* __restrict__ out)
{
    __shared__ u16 As[128 * 32];
    __shared__ u16 Ba[128 * 32];
    __shared__ u16 Bg[128 * 32];
    const int t    = threadIdx.x;
    const int lane = t & 63;
    const int wv   = t >> 6;
    const int wm   = wv >> 1, wn = wv & 1;
    const int lm   = lane & 15, lq = lane >> 4;
    const int m0   = blockIdx.x * 128, n0 = blockIdx.y * 128;
    floatx4 accA[4][4] = {};
    floatx4 accG[4][4] = {};
    for (int k0 = 0; k0 < 512; k0 += 32) {
        stage_tile_128x32(A, As, m0, k0);
        stage_tile_128x32(Wo, Ba, n0, k0);
        stage_tile_128x32(Wo, Bg, 512 + n0, k0);
        __syncthreads();
        bf16x8 af[4], ba[4], bg[4];
        #pragma unroll
        for (int i = 0; i < 4; ++i)
            af[i] = *(const bf16x8*)&As[(wm * 64 + i * 16 + lm) * 32 + lq * 8];
        #pragma unroll
        for (int j = 0; j < 4; ++j) {
            ba[j] = *(const bf16x8*)&Ba[(wn * 64 + j * 16 + lm) * 32 + lq * 8];
            bg[j] = *(const bf16x8*)&Bg[(wn * 64 + j * 16 + lm) * 32 + lq * 8];
        }
        #pragma unroll
        for (int i = 0; i < 4; ++i) {
            #pragma unroll
            for (int j = 0; j < 4; ++j) {
                accA[i][j] = __builtin_amdgcn_mfma_f32_16x16x32_bf16(af[i], ba[j], accA[i][j], 0, 0, 0);
                accG[i][j] = __builtin_amdgcn_mfma_f32_16x16x32_bf16(af[i], bg[j], accG[i][j], 0, 0, 0);
            }
        }
        __syncthreads();
    }
    #pragma unroll
    for (int j = 0; j < 4; ++j) {
        int n = n0 + wn * 64 + j * 16 + lm;
        float bav = bo[n], bgv = bo[512 + n];
        #pragma unroll
        for (int i = 0; i < 4; ++i) {
            #pragma unroll
            for (int r = 0; r < 4; ++r) {
                int m = m0 + wm * 64 + i * 16 + lq * 4 + r;
                float av = accA[i][j][r] + bav;
                float gv = accG[i][j][r] + bgv;
                float xv = x[(size_t)m * 512 + n];
                out[(size_t)m * 512 + n] = f2b(fmaf(av, sigmoidf_(gv), xv));
            }
        }
    }
}

// ---------------------------------------------------------------------------
// 6/7) MFMA GEMM: C_bf16 = act(A[M,512]·Bw[512,512]^T + bias). EPI: 1=relu
// ---------------------------------------------------------------------------
template<int EPI>
__global__ __launch_bounds__(256) void gemm_bt_bf_kernel(
    const u16* __restrict__ A, const u16* __restrict__ Bw,
    const float* __restrict__ bias, u16* __restrict__ C)
{
    __shared__ u16 As[128 * 32];
    __shared__ u16 Bs[128 * 32];
    const int t    = threadIdx.x;
    const int lane = t & 63;
    const int wv   = t >> 6;
    const int wm   = wv >> 1, wn = wv & 1;
    const int lm   = lane & 15, lq = lane >> 4;
    const int m0   = blockIdx.x * 128, n0 = blockIdx.y * 128;
    floatx4 acc[4][4] = {};
    for (int k0 = 0; k0 < 512; k0 += 32) {
        stage_tile_128x32(A, As, m0, k0);
        stage_tile_128x32(Bw, Bs, n0, k0);
        __syncthreads();
        bf16x8 af[4], bfr[4];
        #pragma unroll
        for (int i = 0; i < 4; ++i)
            af[i] = *(const bf16x8*)&As[(wm * 64 + i * 16 + lm) * 32 + lq * 8];
        #pragma unroll
        for (int j = 0; j < 4; ++j)
            bfr[j] = *(const bf16x8*)&Bs[(wn * 64 + j * 16 + lm) * 32 + lq * 8];
        #pragma unroll
        for (int i = 0; i < 4; ++i) {
            #pragma unroll
            for (int j = 0; j < 4; ++j)
                acc[i][j] = __builtin_amdgcn_mfma_f32_16x16x32_bf16(af[i], bfr[j], acc[i][j], 0, 0, 0);
        }
        __syncthreads();
    }
    #pragma unroll
    for (int j = 0; j < 4; ++j) {
        int n = n0 + wn * 64 + j * 16 + lm;
        float bv = bias[n];
        #pragma unroll
        for (int i = 0; i < 4; ++i) {
            #pragma unroll
            for (int r = 0; r < 4; ++r) {
                int m = m0 + wm * 64 + i * 16 + lq * 4 + r;
                float v = acc[i][j][r] + bv;
                if (EPI == 1) v = fmaxf(v, 0.0f);
                C[(size_t)m * 512 + n] = f2b(v);
            }
        }
    }
}

// ---------------------------------------------------------------------------
// 8) LayerNorm over H=512; bf16 in, optional bf16 residual; out bf16 or fp32
// ---------------------------------------------------------------------------
template<bool HASRES, bool F32OUT>
__global__ __launch_bounds__(256) void ln_bf_kernel(
    const u16* __restrict__ in, const u16* __restrict__ res,
    const float* __restrict__ gamma, const float* __restrict__ beta,
    u16* __restrict__ outb, float* __restrict__ outf)
{
    int w    = threadIdx.x >> 6;
    int lane = threadIdx.x & 63;
    size_t row  = (size_t)blockIdx.x * 4 + w;
    size_t base = row * 512 + lane * 8;
    uint4 raw = *(const uint4*)(in + base);
    float v[8];
    unpack2(raw.x, v[0], v[1]); unpack2(raw.y, v[2], v[3]);
    unpack2(raw.z, v[4], v[5]); unpack2(raw.w, v[6], v[7]);
    if (HASRES) {
        uint4 rr = *(const uint4*)(res + base);
        float rv[8];
        unpack2(rr.x, rv[0], rv[1]); unpack2(rr.y, rv[2], rv[3]);
        unpack2(rr.z, rv[4], rv[5]); unpack2(rr.w, rv[6], rv[7]);
        #pragma unroll
        for (int i = 0; i < 8; ++i) v[i] += rv[i];
    }
    float s = 0.0f, sq = 0.0f;
    #pragma unroll
    for (int i = 0; i < 8; ++i) { s += v[i]; sq = fmaf(v[i], v[i], sq); }
    #pragma unroll
    for (int m = 32; m > 0; m >>= 1) {
        s  += __shfl_xor(s, m, 64);
        sq += __shfl_xor(sq, m, 64);
    }
    float mu  = s * (1.0f / 512.0f);
    float var = sq * (1.0f / 512.0f) - mu * mu;
    float rs  = rsqrtf(var + 1e-5f);
    float g[8], bt[8];
    *(float4*)&g[0]  = *(const float4*)(gamma + lane * 8);
    *(float4*)&g[4]  = *(const float4*)(gamma + lane * 8 + 4);
    *(float4*)&bt[0] = *(const float4*)(beta + lane * 8);
    *(float4*)&bt[4] = *(const float4*)(beta + lane * 8 + 4);
    float o[8];
    #pragma unroll
    for (int i = 0; i < 8; ++i)
        o[i] = fmaf((v[i] - mu) * rs, g[i], bt[i]);
    if (F32OUT) {
        *(float4*)(outf + base)     = *(float4*)&o[0];
        *(float4*)(outf + base + 4) = *(float4*)&o[4];
    } else {
        uint4 p;
        p.x = pack2(o[0], o[1]); p.y = pack2(o[2], o[3]);
        p.z = pack2(o[4], o[5]); p.w = pack2(o[6], o[7]);
        *(uint4*)(outb + base) = p;
    }
}

// ---------------------------------------------------------------------------
extern "C" void kernel_launch(void* const* d_in, const int* in_sizes, int n_in,
                              void* d_out, int out_size, void* d_ws, size_t ws_size,
                              hipStream_t stream)
{
    (void)in_sizes; (void)n_in; (void)out_size; (void)ws_size;
    const float* x      = (const float*)d_in[0];
    const float* log_dt = (const float*)d_in[1];
    const float* A_re   = (const float*)d_in[2];
    const float* A_im   = (const float*)d_in[3];
    const float* C_re   = (const float*)d_in[4];
    const float* C_im   = (const float*)d_in[5];
    const float* D_skip = (const float*)d_in[6];
    const float* W_out  = (const float*)d_in[7];
    const float* b_out  = (const float*)d_in[8];
    const float* g1     = (const float*)d_in[9];
    const float* beta1  = (const float*)d_in[10];
    const float* g2     = (const float*)d_in[11];
    const float* beta2  = (const float*)d_in[12];
    const float* W1     = (const float*)d_in[13];
    const float* bc1    = (const float*)d_in[14];
    const float* W2     = (const float*)d_in[15];
    const float* bc2    = (const float*)d_in[16];
    float* out = (float*)d_out;

    // workspace: P 512K | Ktab 128K | Toep_bf 4M | weights 2M | r1/r2/r3 bf16 BLH
    char*  wsb    = (char*)d_ws;
    float* P      = (float*)wsb;
    float* Ktab   = (float*)(wsb + 4 * HN * 4);
    u16*   Toep   = (u16*)(wsb + 4 * HN * 4 + 512 * 64 * 4);
    u16*   Wobf   = Toep + 512 * 4096;
    u16*   W1bf   = Wobf + 1024 * 512;
    u16*   W2bf   = W1bf + 512 * 512;
    u16*   r1     = W2bf + 512 * 512;   // XT -> x1n_bf
    u16*   r2     = r1 + BLH;           // YT -> x1pre_bf -> y2_bf
    u16*   r3     = r2 + BLH;           // Y  -> h1_bf

    cast_kernel<<<512, 256, 0, stream>>>(W_out, Wobf);
    cast_kernel<<<256, 256, 0, stream>>>(W1, W1bf);
    cast_kernel<<<256, 256, 0, stream>>>(W2, W2bf);
    precompute_kernel<<<HN / 256, 256, 0, stream>>>(log_dt, A_re, A_im, C_re, C_im, P);
    ktab_kernel<<<128, 256, 0, stream>>>(P, Ktab);
    toepfill_kernel<<<8192, 256, 0, stream>>>(Ktab, Toep);
    xtrans_kernel<<<dim3(L_DIM / 32, H_DIM / 32, B_DIM), 256, 0, stream>>>(x, r1);
    ssm_chunk_kernel<<<dim3(H_DIM, 2), 256, 0, stream>>>(r1, P, Toep, D_skip, r2);
    ytrans_kernel<<<dim3(L_DIM / 32, H_DIM / 32, B_DIM), 256, 0, stream>>>(r2, r3);
    gemm1_glu_kernel<<<dim3(M_DIM / 128, 4), 256, 0, stream>>>(r3, Wobf, b_out, x, r2);
    ln_bf_kernel<false, false><<<M_DIM / 4, 256, 0, stream>>>(r2, nullptr, g1, beta1, r1, nullptr);
    gemm_bt_bf_kernel<1><<<dim3(M_DIM / 128, 4), 256, 0, stream>>>(r1, W1bf, bc1, r3);
    gemm_bt_bf_kernel<0><<<dim3(M_DIM / 128, 4), 256, 0, stream>>>(r3, W2bf, bc2, r2);
    ln_bf_kernel<true, true><<<M_DIM / 4, 256, 0, stream>>>(r2, r1, g2, beta2, nullptr, out);
}